// Round 1
// baseline (5281.681 us; speedup 1.0000x reference)
//
#include <hip/hip_runtime.h>

#define N_NODES  50000
#define N_EDGES  1600000
#define N_FEAT   50
#define HID      20
#define OUT_DIM  10
#define N_GRAPHS 64

// Layer 1 GEMM: y = x @ W_rel (N x 20), acc = x @ W_root + b (N x 20)
__global__ __launch_bounds__(256) void gemm50(const float* __restrict__ x,
        const float* __restrict__ Wrel, const float* __restrict__ Wroot,
        const float* __restrict__ b,
        float* __restrict__ y, float* __restrict__ acc) {
    __shared__ float sWrel[N_FEAT * HID];
    __shared__ float sWroot[N_FEAT * HID];
    for (int i = threadIdx.x; i < N_FEAT * HID; i += 256) {
        sWrel[i]  = Wrel[i];
        sWroot[i] = Wroot[i];
    }
    __syncthreads();
    int idx = blockIdx.x * 256 + threadIdx.x;
    if (idx >= N_NODES * HID) return;
    int n = idx / HID, j = idx % HID;
    const float* xr = x + n * N_FEAT;
    float a0 = 0.0f, a1 = b[j];
    #pragma unroll
    for (int k = 0; k < N_FEAT; ++k) {
        float xv = xr[k];
        a0 = fmaf(xv, sWrel[k * HID + j], a0);
        a1 = fmaf(xv, sWroot[k * HID + j], a1);
    }
    y[idx]   = a0;
    acc[idx] = a1;
}

// Layers 2/3 GEMM: input is pre-relu acc of previous layer; relu applied on read.
__global__ __launch_bounds__(256) void gemm20(const float* __restrict__ hin,
        const float* __restrict__ Wrel, const float* __restrict__ Wroot,
        const float* __restrict__ b,
        float* __restrict__ y, float* __restrict__ acc) {
    __shared__ float sWrel[HID * HID];
    __shared__ float sWroot[HID * HID];
    for (int i = threadIdx.x; i < HID * HID; i += 256) {
        sWrel[i]  = Wrel[i];
        sWroot[i] = Wroot[i];
    }
    __syncthreads();
    int idx = blockIdx.x * 256 + threadIdx.x;
    if (idx >= N_NODES * HID) return;
    int n = idx / HID, j = idx % HID;
    const float* hr = hin + n * HID;
    float a0 = 0.0f, a1 = b[j];
    #pragma unroll
    for (int k = 0; k < HID; ++k) {
        float hv = fmaxf(hr[k], 0.0f);
        a0 = fmaf(hv, sWrel[k * HID + j], a0);
        a1 = fmaf(hv, sWroot[k * HID + j], a1);
    }
    y[idx]   = a0;
    acc[idx] = a1;
}

// Edge scatter: acc[dst] += y[src] (20 floats per edge)
__global__ __launch_bounds__(256) void scatter_add(const int* __restrict__ src,
        const int* __restrict__ dst, const float* __restrict__ y,
        float* __restrict__ acc) {
    int e = blockIdx.x * 256 + threadIdx.x;
    if (e >= N_EDGES) return;
    int s = src[e], d = dst[e];
    const float4* yr = (const float4*)(y + s * HID);  // 80B row, 16B aligned
    float* ar = acc + d * HID;
    float4 v0 = yr[0], v1 = yr[1], v2 = yr[2], v3 = yr[3], v4 = yr[4];
    atomicAdd(ar + 0,  v0.x); atomicAdd(ar + 1,  v0.y);
    atomicAdd(ar + 2,  v0.z); atomicAdd(ar + 3,  v0.w);
    atomicAdd(ar + 4,  v1.x); atomicAdd(ar + 5,  v1.y);
    atomicAdd(ar + 6,  v1.z); atomicAdd(ar + 7,  v1.w);
    atomicAdd(ar + 8,  v2.x); atomicAdd(ar + 9,  v2.y);
    atomicAdd(ar + 10, v2.z); atomicAdd(ar + 11, v2.w);
    atomicAdd(ar + 12, v3.x); atomicAdd(ar + 13, v3.y);
    atomicAdd(ar + 14, v3.z); atomicAdd(ar + 15, v3.w);
    atomicAdd(ar + 16, v4.x); atomicAdd(ar + 17, v4.y);
    atomicAdd(ar + 18, v4.z); atomicAdd(ar + 19, v4.w);
}

__global__ void init_pool(float* __restrict__ maxP, float* __restrict__ sumP,
                          float* __restrict__ cnt) {
    int i = blockIdx.x * blockDim.x + threadIdx.x;
    if (i < N_GRAPHS * HID) { maxP[i] = 0.0f; sumP[i] = 0.0f; }
    if (i < N_GRAPHS) cnt[i] = 0.0f;
}

// Pool: per-graph max & sum of relu(acc3). relu output >= 0 so int-bit
// atomicMax is order-preserving with init 0.
__global__ __launch_bounds__(256) void pool(const float* __restrict__ acc,
        const int* __restrict__ batch, float* __restrict__ maxP,
        float* __restrict__ sumP, float* __restrict__ cnt) {
    int idx = blockIdx.x * 256 + threadIdx.x;
    if (idx >= N_NODES * HID) return;
    int n = idx / HID, j = idx % HID;
    int g = batch[n];
    float v = fmaxf(acc[idx], 0.0f);
    atomicMax((int*)&maxP[g * HID + j], __float_as_int(v));
    atomicAdd(&sumP[g * HID + j], v);
    if (j == 0) atomicAdd(&cnt[g], 1.0f);
}

// out[g][o] = b[o] + sum_j maxP[g][j]*W[j][o] + meanP[g][j]*W[20+j][o]
__global__ void final_lin(const float* __restrict__ maxP, const float* __restrict__ sumP,
        const float* __restrict__ cnt, const float* __restrict__ Wlin,
        const float* __restrict__ blin, float* __restrict__ out) {
    __shared__ float sW[2 * HID * OUT_DIM];
    for (int i = threadIdx.x; i < 2 * HID * OUT_DIM; i += blockDim.x) sW[i] = Wlin[i];
    __syncthreads();
    int idx = threadIdx.x;
    if (idx >= N_GRAPHS * OUT_DIM) return;
    int g = idx / OUT_DIM, o = idx % OUT_DIM;
    float c = fmaxf(cnt[g], 1.0f);
    float a = blin[o];
    #pragma unroll
    for (int j = 0; j < HID; ++j) {
        a = fmaf(maxP[g * HID + j], sW[j * OUT_DIM + o], a);
        a = fmaf(sumP[g * HID + j] / c, sW[(HID + j) * OUT_DIM + o], a);
    }
    out[idx] = a;
}

extern "C" void kernel_launch(void* const* d_in, const int* in_sizes, int n_in,
                              void* d_out, int out_size, void* d_ws, size_t ws_size,
                              hipStream_t stream) {
    const float* x      = (const float*)d_in[0];
    const int*   ei     = (const int*)  d_in[1];
    const int*   batch  = (const int*)  d_in[2];
    const float* Wrel1  = (const float*)d_in[3];
    const float* Wroot1 = (const float*)d_in[4];
    const float* b1     = (const float*)d_in[5];
    const float* Wrel2  = (const float*)d_in[6];
    const float* Wroot2 = (const float*)d_in[7];
    const float* b2     = (const float*)d_in[8];
    const float* Wrel3  = (const float*)d_in[9];
    const float* Wroot3 = (const float*)d_in[10];
    const float* b3     = (const float*)d_in[11];
    const float* Wlin   = (const float*)d_in[12];
    const float* blin   = (const float*)d_in[13];
    float* out = (float*)d_out;

    char* ws = (char*)d_ws;
    const size_t NB = (size_t)N_NODES * HID * sizeof(float);  // 4,000,000 B
    float* y    = (float*)(ws);
    float* accA = (float*)(ws + NB);
    float* accB = (float*)(ws + 2 * NB);
    float* maxP = (float*)(ws + 3 * NB);
    float* sumP = maxP + N_GRAPHS * HID;
    float* cnt  = sumP + N_GRAPHS * HID;

    const int* src = ei;
    const int* dst = ei + N_EDGES;

    const int gN = (N_NODES * HID + 255) / 256;  // 3907
    const int gE = (N_EDGES + 255) / 256;        // 6250

    // Layer 1
    gemm50<<<gN, 256, 0, stream>>>(x, Wrel1, Wroot1, b1, y, accA);
    scatter_add<<<gE, 256, 0, stream>>>(src, dst, y, accA);
    // Layer 2
    gemm20<<<gN, 256, 0, stream>>>(accA, Wrel2, Wroot2, b2, y, accB);
    scatter_add<<<gE, 256, 0, stream>>>(src, dst, y, accB);
    // Layer 3
    gemm20<<<gN, 256, 0, stream>>>(accB, Wrel3, Wroot3, b3, y, accA);
    scatter_add<<<gE, 256, 0, stream>>>(src, dst, y, accA);
    // Pooling + final linear
    init_pool<<<5, 256, 0, stream>>>(maxP, sumP, cnt);
    pool<<<gN, 256, 0, stream>>>(accA, batch, maxP, sumP, cnt);
    final_lin<<<1, 640, 0, stream>>>(maxP, sumP, cnt, Wlin, blin, out);
}

// Round 2
// 436.684 us; speedup vs baseline: 12.0950x; 12.0950x over previous
//
#include <hip/hip_runtime.h>

#define N_NODES  50000
#define N_EDGES  1600000
#define N_FEAT   50
#define HID      20
#define OUT_DIM  10
#define N_GRAPHS 64

// ---------------- GEMMs (tiny: 50k x {50,20} @ {50,20}x20) ----------------

__global__ __launch_bounds__(256) void gemm50(const float* __restrict__ x,
        const float* __restrict__ Wrel, const float* __restrict__ Wroot,
        const float* __restrict__ b,
        float* __restrict__ y, float* __restrict__ acc) {
    __shared__ float sWrel[N_FEAT * HID];
    __shared__ float sWroot[N_FEAT * HID];
    for (int i = threadIdx.x; i < N_FEAT * HID; i += 256) {
        sWrel[i]  = Wrel[i];
        sWroot[i] = Wroot[i];
    }
    __syncthreads();
    int idx = blockIdx.x * 256 + threadIdx.x;
    if (idx >= N_NODES * HID) return;
    int n = idx / HID, j = idx % HID;
    const float* xr = x + n * N_FEAT;
    float a0 = 0.0f, a1 = b[j];
    #pragma unroll
    for (int k = 0; k < N_FEAT; ++k) {
        float xv = xr[k];
        a0 = fmaf(xv, sWrel[k * HID + j], a0);
        a1 = fmaf(xv, sWroot[k * HID + j], a1);
    }
    y[idx]   = a0;
    acc[idx] = a1;
}

__global__ __launch_bounds__(256) void gemm20(const float* __restrict__ hin,
        const float* __restrict__ Wrel, const float* __restrict__ Wroot,
        const float* __restrict__ b,
        float* __restrict__ y, float* __restrict__ acc) {
    __shared__ float sWrel[HID * HID];
    __shared__ float sWroot[HID * HID];
    for (int i = threadIdx.x; i < HID * HID; i += 256) {
        sWrel[i]  = Wrel[i];
        sWroot[i] = Wroot[i];
    }
    __syncthreads();
    int idx = blockIdx.x * 256 + threadIdx.x;
    if (idx >= N_NODES * HID) return;
    int n = idx / HID, j = idx % HID;
    const float* hr = hin + n * HID;
    float a0 = 0.0f, a1 = b[j];
    #pragma unroll
    for (int k = 0; k < HID; ++k) {
        float hv = fmaxf(hr[k], 0.0f);
        a0 = fmaf(hv, sWrel[k * HID + j], a0);
        a1 = fmaf(hv, sWroot[k * HID + j], a1);
    }
    y[idx]   = a0;
    acc[idx] = a1;
}

// ---------------- CSR build (by dst) ----------------

__global__ __launch_bounds__(256) void hist(const int* __restrict__ dst,
                                            int* __restrict__ deg) {
    int e = blockIdx.x * 256 + threadIdx.x;
    if (e < N_EDGES) atomicAdd(&deg[dst[e]], 1);
}

#define SCAN_T 1024
#define CHUNK ((N_NODES + SCAN_T - 1) / SCAN_T)  // 49

__global__ __launch_bounds__(SCAN_T) void scan_deg(const int* __restrict__ deg,
        int* __restrict__ offs, int* __restrict__ cursor) {
    __shared__ int part[SCAN_T];
    int t = threadIdx.x;
    int s0 = t * CHUNK;
    int s1 = min(s0 + CHUNK, N_NODES);
    int s = 0;
    for (int i = s0; i < s1; ++i) s += deg[i];
    part[t] = s;
    __syncthreads();
    // Hillis-Steele inclusive scan over 1024 partials
    for (int d = 1; d < SCAN_T; d <<= 1) {
        int v = (t >= d) ? part[t - d] : 0;
        __syncthreads();
        part[t] += v;
        __syncthreads();
    }
    int run = (t == 0) ? 0 : part[t - 1];
    for (int i = s0; i < s1; ++i) {
        offs[i] = run;
        cursor[i] = run;
        run += deg[i];
    }
    if (t == SCAN_T - 1) offs[N_NODES] = N_EDGES;
}

__global__ __launch_bounds__(256) void fill_csr(const int* __restrict__ src,
        const int* __restrict__ dst, int* __restrict__ cursor,
        int* __restrict__ csr) {
    int e = blockIdx.x * 256 + threadIdx.x;
    if (e < N_EDGES) {
        int p = atomicAdd(&cursor[dst[e]], 1);
        csr[p] = src[e];
    }
}

// ---------------- Gather: acc[n] += sum over in-edges of y[src] ----------------
// 5 threads per node, one float4 (4 feats) each. Block 320 = 64 nodes.

__global__ __launch_bounds__(320) void gather(const int* __restrict__ offs,
        const int* __restrict__ csr, const float* __restrict__ y,
        float* __restrict__ acc) {
    int node = blockIdx.x * 64 + threadIdx.x / 5;
    int q = threadIdx.x % 5;
    if (node >= N_NODES) return;
    int a = offs[node], b = offs[node + 1];
    float4 s = make_float4(0.f, 0.f, 0.f, 0.f);
    #pragma unroll 4
    for (int k = a; k < b; ++k) {
        int sn = csr[k];
        float4 v = *(const float4*)(y + sn * HID + q * 4);
        s.x += v.x; s.y += v.y; s.z += v.z; s.w += v.w;
    }
    float4* ap = (float4*)(acc + node * HID) + q;
    float4 o = *ap;
    o.x += s.x; o.y += s.y; o.z += s.z; o.w += s.w;
    *ap = o;
}

// ---------------- Pool (block per graph, batch sorted) + final linear ----------------

__global__ __launch_bounds__(320) void pool_final(const float* __restrict__ acc,
        const int* __restrict__ batch, const float* __restrict__ Wlin,
        const float* __restrict__ blin, float* __restrict__ out) {
    int g = blockIdx.x;
    __shared__ int se[2];
    if (threadIdx.x < 2) {
        int target = g + threadIdx.x;  // lower_bound(batch, target)
        int lo = 0, hi = N_NODES;
        while (lo < hi) {
            int mid = (lo + hi) >> 1;
            if (batch[mid] < target) lo = mid + 1; else hi = mid;
        }
        se[threadIdx.x] = lo;
    }
    __syncthreads();
    int s = se[0], e = se[1];
    int j = threadIdx.x % HID;
    int r = threadIdx.x / HID;  // 0..15
    float mx = 0.0f, sm = 0.0f;
    for (int n = s + r; n < e; n += 16) {
        float v = fmaxf(acc[n * HID + j], 0.0f);
        mx = fmaxf(mx, v);
        sm += v;
    }
    __shared__ float smx[16][HID];
    __shared__ float ssm[16][HID];
    smx[r][j] = mx;
    ssm[r][j] = sm;
    __syncthreads();
    if (threadIdx.x < HID) {
        float m = 0.0f, su = 0.0f;
        #pragma unroll
        for (int r2 = 0; r2 < 16; ++r2) {
            m = fmaxf(m, smx[r2][threadIdx.x]);
            su += ssm[r2][threadIdx.x];
        }
        smx[0][threadIdx.x] = m;
        ssm[0][threadIdx.x] = su / fmaxf((float)(e - s), 1.0f);
    }
    __syncthreads();
    if (threadIdx.x < OUT_DIM) {
        int o = threadIdx.x;
        float a = blin[o];
        #pragma unroll
        for (int jj = 0; jj < HID; ++jj) {
            a = fmaf(smx[0][jj], Wlin[jj * OUT_DIM + o], a);
            a = fmaf(ssm[0][jj], Wlin[(HID + jj) * OUT_DIM + o], a);
        }
        out[g * OUT_DIM + o] = a;
    }
}

extern "C" void kernel_launch(void* const* d_in, const int* in_sizes, int n_in,
                              void* d_out, int out_size, void* d_ws, size_t ws_size,
                              hipStream_t stream) {
    const float* x      = (const float*)d_in[0];
    const int*   ei     = (const int*)  d_in[1];
    const int*   batch  = (const int*)  d_in[2];
    const float* Wrel1  = (const float*)d_in[3];
    const float* Wroot1 = (const float*)d_in[4];
    const float* b1     = (const float*)d_in[5];
    const float* Wrel2  = (const float*)d_in[6];
    const float* Wroot2 = (const float*)d_in[7];
    const float* b2     = (const float*)d_in[8];
    const float* Wrel3  = (const float*)d_in[9];
    const float* Wroot3 = (const float*)d_in[10];
    const float* b3     = (const float*)d_in[11];
    const float* Wlin   = (const float*)d_in[12];
    const float* blin   = (const float*)d_in[13];
    float* out = (float*)d_out;

    char* ws = (char*)d_ws;
    const size_t NB = (size_t)N_NODES * HID * sizeof(float);  // 4,000,000 B
    float* y      = (float*)(ws);
    float* accA   = (float*)(ws + NB);
    float* accB   = (float*)(ws + 2 * NB);
    int*   csr    = (int*)  (ws + 3 * NB);                    // 6,400,000 B
    int*   deg    = (int*)  (ws + 3 * NB + (size_t)N_EDGES * 4);
    int*   cursor = deg + N_NODES;
    int*   offs   = cursor + N_NODES;                         // N_NODES+1 ints

    const int* src = ei;
    const int* dst = ei + N_EDGES;

    const int gN = (N_NODES * HID + 255) / 256;   // 3907
    const int gE = (N_EDGES + 255) / 256;         // 6250
    const int gG = (N_NODES + 63) / 64;           // 782

    // ---- CSR build (same every call; must rebuild deterministically) ----
    hipMemsetAsync(deg, 0, N_NODES * sizeof(int), stream);
    hist<<<gE, 256, 0, stream>>>(dst, deg);
    scan_deg<<<1, SCAN_T, 0, stream>>>(deg, offs, cursor);
    fill_csr<<<gE, 256, 0, stream>>>(src, dst, cursor, csr);

    // ---- Layer 1 ----
    gemm50<<<gN, 256, 0, stream>>>(x, Wrel1, Wroot1, b1, y, accA);
    gather<<<gG, 320, 0, stream>>>(offs, csr, y, accA);
    // ---- Layer 2 ----
    gemm20<<<gN, 256, 0, stream>>>(accA, Wrel2, Wroot2, b2, y, accB);
    gather<<<gG, 320, 0, stream>>>(offs, csr, y, accB);
    // ---- Layer 3 ----
    gemm20<<<gN, 256, 0, stream>>>(accB, Wrel3, Wroot3, b3, y, accA);
    gather<<<gG, 320, 0, stream>>>(offs, csr, y, accA);

    // ---- Pool + final linear ----
    pool_final<<<N_GRAPHS, 320, 0, stream>>>(accA, batch, Wlin, blin, out);
}

// Round 3
// 399.331 us; speedup vs baseline: 13.2263x; 1.0935x over previous
//
#include <hip/hip_runtime.h>

#define N_NODES  50000
#define N_EDGES  1600000
#define N_FEAT   50
#define HID      20
#define OUT_DIM  10
#define N_GRAPHS 64

// ---------------- Layer-1 GEMM: y = x@Wrel, acc = x@Wroot + b ----------------

__global__ __launch_bounds__(256) void gemm50(const float* __restrict__ x,
        const float* __restrict__ Wrel, const float* __restrict__ Wroot,
        const float* __restrict__ b,
        float* __restrict__ y, float* __restrict__ acc) {
    __shared__ float sWrel[N_FEAT * HID];
    __shared__ float sWroot[N_FEAT * HID];
    for (int i = threadIdx.x; i < N_FEAT * HID; i += 256) {
        sWrel[i]  = Wrel[i];
        sWroot[i] = Wroot[i];
    }
    __syncthreads();
    int idx = blockIdx.x * 256 + threadIdx.x;
    if (idx >= N_NODES * HID) return;
    int n = idx / HID, j = idx % HID;
    const float* xr = x + n * N_FEAT;
    float a0 = 0.0f, a1 = b[j];
    #pragma unroll
    for (int k = 0; k < N_FEAT; ++k) {
        float xv = xr[k];
        a0 = fmaf(xv, sWrel[k * HID + j], a0);
        a1 = fmaf(xv, sWroot[k * HID + j], a1);
    }
    y[idx]   = a0;
    acc[idx] = a1;
}

// ---------------- CSR build (by dst) ----------------

// 4 edges/thread for 4 outstanding atomics (latency hiding).
__global__ __launch_bounds__(256) void hist(const int* __restrict__ dst,
                                            int* __restrict__ deg) {
    int t = blockIdx.x * 256 + threadIdx.x;
    int e0 = t * 4;
    if (e0 >= N_EDGES) return;  // N_EDGES % 4 == 0
    int4 d4 = *(const int4*)(dst + e0);
    atomicAdd(&deg[d4.x], 1);
    atomicAdd(&deg[d4.y], 1);
    atomicAdd(&deg[d4.z], 1);
    atomicAdd(&deg[d4.w], 1);
}

// Single-block scan, coalesced tile loads + wave shfl-scan.
__global__ __launch_bounds__(1024) void scan_deg(const int* __restrict__ deg,
        int* __restrict__ offs, int* __restrict__ cursor) {
    __shared__ int wsum[16];
    __shared__ int carry_s;
    int t = threadIdx.x;
    int lane = t & 63, w = t >> 6;
    if (t == 0) carry_s = 0;
    __syncthreads();
    for (int base = 0; base < N_NODES; base += 1024) {
        int i = base + t;
        int v = (i < N_NODES) ? deg[i] : 0;
        int sc = v;  // inclusive wave scan
        #pragma unroll
        for (int d = 1; d < 64; d <<= 1) {
            int u = __shfl_up(sc, d, 64);
            if (lane >= d) sc += u;
        }
        if (lane == 63) wsum[w] = sc;
        __syncthreads();
        int wpre = 0;
        for (int k = 0; k < w; ++k) wpre += wsum[k];
        int excl = carry_s + wpre + sc - v;
        if (i < N_NODES) { offs[i] = excl; cursor[i] = excl; }
        __syncthreads();
        if (t == 1023) carry_s += wpre + sc;  // tile total
        __syncthreads();
    }
    if (t == 0) offs[N_NODES] = N_EDGES;
}

// 4 edges/thread: 4 independent returning atomics in flight, then 4 stores.
__global__ __launch_bounds__(256) void fill_csr(const int* __restrict__ src,
        const int* __restrict__ dst, int* __restrict__ cursor,
        int* __restrict__ csr) {
    int t = blockIdx.x * 256 + threadIdx.x;
    int e0 = t * 4;
    if (e0 >= N_EDGES) return;
    int4 d4 = *(const int4*)(dst + e0);
    int4 s4 = *(const int4*)(src + e0);
    int p0 = atomicAdd(&cursor[d4.x], 1);
    int p1 = atomicAdd(&cursor[d4.y], 1);
    int p2 = atomicAdd(&cursor[d4.z], 1);
    int p3 = atomicAdd(&cursor[d4.w], 1);
    csr[p0] = s4.x;
    csr[p1] = s4.y;
    csr[p2] = s4.z;
    csr[p3] = s4.w;
}

// ---------------- Fused gather + next-layer GEMM ----------------
// Per node: agg = sum_{in-edges} y_in[src]; h = accp + agg; rh = relu(h);
// y_out = rh@Wrel, acc_out = rh@Wroot + b.
// 5 threads/node (4 feats each), 64 nodes/block.

__global__ __launch_bounds__(320) void gather_gemm(const int* __restrict__ offs,
        const int* __restrict__ cend, const int* __restrict__ csr,
        const float* __restrict__ y_in, const float* __restrict__ accp,
        const float* __restrict__ Wrel, const float* __restrict__ Wroot,
        const float* __restrict__ b,
        float* __restrict__ y_out, float* __restrict__ acc_out) {
    __shared__ float sWrel[HID * HID];
    __shared__ float sWroot[HID * HID];
    __shared__ float sb[HID];
    __shared__ float rh[64][HID];
    for (int i = threadIdx.x; i < HID * HID; i += 320) {
        sWrel[i]  = Wrel[i];
        sWroot[i] = Wroot[i];
    }
    if (threadIdx.x < HID) sb[threadIdx.x] = b[threadIdx.x];
    int local = threadIdx.x / 5;
    int q     = threadIdx.x % 5;
    int node  = blockIdx.x * 64 + local;
    bool valid = node < N_NODES;
    if (valid) {
        int a = offs[node], e = cend[node];
        float4 s0 = make_float4(0.f, 0.f, 0.f, 0.f);
        float4 s1 = make_float4(0.f, 0.f, 0.f, 0.f);
        int k = a;
        for (; k + 1 < e; k += 2) {
            int sn0 = csr[k], sn1 = csr[k + 1];
            float4 v0 = *(const float4*)(y_in + sn0 * HID + q * 4);
            float4 v1 = *(const float4*)(y_in + sn1 * HID + q * 4);
            s0.x += v0.x; s0.y += v0.y; s0.z += v0.z; s0.w += v0.w;
            s1.x += v1.x; s1.y += v1.y; s1.z += v1.z; s1.w += v1.w;
        }
        if (k < e) {
            int sn = csr[k];
            float4 v = *(const float4*)(y_in + sn * HID + q * 4);
            s0.x += v.x; s0.y += v.y; s0.z += v.z; s0.w += v.w;
        }
        float4 av = *((const float4*)(accp + node * HID) + q);
        rh[local][q * 4 + 0] = fmaxf(av.x + s0.x + s1.x, 0.f);
        rh[local][q * 4 + 1] = fmaxf(av.y + s0.y + s1.y, 0.f);
        rh[local][q * 4 + 2] = fmaxf(av.z + s0.z + s1.z, 0.f);
        rh[local][q * 4 + 3] = fmaxf(av.w + s0.w + s1.w, 0.f);
    }
    __syncthreads();
    if (!valid) return;
    int j0 = q * 4;
    float y0 = 0.f, y1 = 0.f, y2 = 0.f, y3 = 0.f;
    float a0 = sb[j0], a1 = sb[j0 + 1], a2 = sb[j0 + 2], a3 = sb[j0 + 3];
    #pragma unroll
    for (int k = 0; k < HID; ++k) {
        float hv = rh[local][k];
        const float* wr = sWrel  + k * HID + j0;
        const float* wo = sWroot + k * HID + j0;
        y0 = fmaf(hv, wr[0], y0); y1 = fmaf(hv, wr[1], y1);
        y2 = fmaf(hv, wr[2], y2); y3 = fmaf(hv, wr[3], y3);
        a0 = fmaf(hv, wo[0], a0); a1 = fmaf(hv, wo[1], a1);
        a2 = fmaf(hv, wo[2], a2); a3 = fmaf(hv, wo[3], a3);
    }
    *((float4*)(y_out   + node * HID) + q) = make_float4(y0, y1, y2, y3);
    *((float4*)(acc_out + node * HID) + q) = make_float4(a0, a1, a2, a3);
}

// Plain gather for final layer: acc[n] += sum y[src]
__global__ __launch_bounds__(320) void gather(const int* __restrict__ offs,
        const int* __restrict__ cend, const int* __restrict__ csr,
        const float* __restrict__ y, float* __restrict__ acc) {
    int node = blockIdx.x * 64 + threadIdx.x / 5;
    int q = threadIdx.x % 5;
    if (node >= N_NODES) return;
    int a = offs[node], e = cend[node];
    float4 s0 = make_float4(0.f, 0.f, 0.f, 0.f);
    float4 s1 = make_float4(0.f, 0.f, 0.f, 0.f);
    int k = a;
    for (; k + 1 < e; k += 2) {
        int sn0 = csr[k], sn1 = csr[k + 1];
        float4 v0 = *(const float4*)(y + sn0 * HID + q * 4);
        float4 v1 = *(const float4*)(y + sn1 * HID + q * 4);
        s0.x += v0.x; s0.y += v0.y; s0.z += v0.z; s0.w += v0.w;
        s1.x += v1.x; s1.y += v1.y; s1.z += v1.z; s1.w += v1.w;
    }
    if (k < e) {
        int sn = csr[k];
        float4 v = *(const float4*)(y + sn * HID + q * 4);
        s0.x += v.x; s0.y += v.y; s0.z += v.z; s0.w += v.w;
    }
    float4* ap = (float4*)(acc + node * HID) + q;
    float4 o = *ap;
    o.x += s0.x + s1.x; o.y += s0.y + s1.y;
    o.z += s0.z + s1.z; o.w += s0.w + s1.w;
    *ap = o;
}

// ---------------- Pool (block per graph, batch sorted) + final linear ----------------

__global__ __launch_bounds__(320) void pool_final(const float* __restrict__ acc,
        const int* __restrict__ batch, const float* __restrict__ Wlin,
        const float* __restrict__ blin, float* __restrict__ out) {
    int g = blockIdx.x;
    __shared__ int se[2];
    if (threadIdx.x < 2) {
        int target = g + threadIdx.x;
        int lo = 0, hi = N_NODES;
        while (lo < hi) {
            int mid = (lo + hi) >> 1;
            if (batch[mid] < target) lo = mid + 1; else hi = mid;
        }
        se[threadIdx.x] = lo;
    }
    __syncthreads();
    int s = se[0], e = se[1];
    int j = threadIdx.x % HID;
    int r = threadIdx.x / HID;
    float mx = 0.0f, sm = 0.0f;
    for (int n = s + r; n < e; n += 16) {
        float v = fmaxf(acc[n * HID + j], 0.0f);
        mx = fmaxf(mx, v);
        sm += v;
    }
    __shared__ float smx[16][HID];
    __shared__ float ssm[16][HID];
    smx[r][j] = mx;
    ssm[r][j] = sm;
    __syncthreads();
    if (threadIdx.x < HID) {
        float m = 0.0f, su = 0.0f;
        #pragma unroll
        for (int r2 = 0; r2 < 16; ++r2) {
            m = fmaxf(m, smx[r2][threadIdx.x]);
            su += ssm[r2][threadIdx.x];
        }
        smx[0][threadIdx.x] = m;
        ssm[0][threadIdx.x] = su / fmaxf((float)(e - s), 1.0f);
    }
    __syncthreads();
    if (threadIdx.x < OUT_DIM) {
        int o = threadIdx.x;
        float a = blin[o];
        #pragma unroll
        for (int jj = 0; jj < HID; ++jj) {
            a = fmaf(smx[0][jj], Wlin[jj * OUT_DIM + o], a);
            a = fmaf(ssm[0][jj], Wlin[(HID + jj) * OUT_DIM + o], a);
        }
        out[g * OUT_DIM + o] = a;
    }
}

extern "C" void kernel_launch(void* const* d_in, const int* in_sizes, int n_in,
                              void* d_out, int out_size, void* d_ws, size_t ws_size,
                              hipStream_t stream) {
    const float* x      = (const float*)d_in[0];
    const int*   ei     = (const int*)  d_in[1];
    const int*   batch  = (const int*)  d_in[2];
    const float* Wrel1  = (const float*)d_in[3];
    const float* Wroot1 = (const float*)d_in[4];
    const float* b1     = (const float*)d_in[5];
    const float* Wrel2  = (const float*)d_in[6];
    const float* Wroot2 = (const float*)d_in[7];
    const float* b2     = (const float*)d_in[8];
    const float* Wrel3  = (const float*)d_in[9];
    const float* Wroot3 = (const float*)d_in[10];
    const float* b3     = (const float*)d_in[11];
    const float* Wlin   = (const float*)d_in[12];
    const float* blin   = (const float*)d_in[13];
    float* out = (float*)d_out;

    char* ws = (char*)d_ws;
    const size_t NB = (size_t)N_NODES * HID * sizeof(float);  // 4,000,000 B
    float* yA     = (float*)(ws);
    float* yB     = (float*)(ws + NB);
    float* accA   = (float*)(ws + 2 * NB);
    float* accB   = (float*)(ws + 3 * NB);
    int*   csr    = (int*)  (ws + 4 * NB);                    // 6,400,000 B
    int*   deg    = (int*)  (ws + 4 * NB + (size_t)N_EDGES * 4);
    int*   cursor = deg + N_NODES;
    int*   offs   = cursor + N_NODES;                         // N_NODES+1 ints

    const int* src = ei;
    const int* dst = ei + N_EDGES;

    const int gN = (N_NODES * HID + 255) / 256;   // 3907
    const int gE4 = (N_EDGES / 4 + 255) / 256;    // 1563
    const int gG = (N_NODES + 63) / 64;           // 782

    // ---- CSR build (rebuilt deterministically every call) ----
    hipMemsetAsync(deg, 0, N_NODES * sizeof(int), stream);
    hist<<<gE4, 256, 0, stream>>>(dst, deg);
    scan_deg<<<1, 1024, 0, stream>>>(deg, offs, cursor);
    fill_csr<<<gE4, 256, 0, stream>>>(src, dst, cursor, csr);
    // After fill: cursor[n] == end offset of node n's bucket.

    // ---- Layer 1 GEMM ----
    gemm50<<<gN, 256, 0, stream>>>(x, Wrel1, Wroot1, b1, yA, accA);
    // ---- Layer 1 gather fused with Layer 2 GEMM ----
    gather_gemm<<<gG, 320, 0, stream>>>(offs, cursor, csr, yA, accA,
                                        Wrel2, Wroot2, b2, yB, accB);
    // ---- Layer 2 gather fused with Layer 3 GEMM ----
    gather_gemm<<<gG, 320, 0, stream>>>(offs, cursor, csr, yB, accB,
                                        Wrel3, Wroot3, b3, yA, accA);
    // ---- Layer 3 gather ----
    gather<<<gG, 320, 0, stream>>>(offs, cursor, csr, yA, accA);

    // ---- Pool + final linear ----
    pool_final<<<N_GRAPHS, 320, 0, stream>>>(accA, batch, Wlin, blin, out);
}

// Round 4
// 166.840 us; speedup vs baseline: 31.6571x; 2.3935x over previous
//
#include <hip/hip_runtime.h>

#define N_NODES  50000
#define N_EDGES  1600000
#define N_FEAT   50
#define HID      20
#define OUT_DIM  10
#define N_GRAPHS 64

#define NBUCK 196            // coarse buckets: dst >> 8 (256 nodes each)
#define BCAP  10240          // padded slots/bucket (avg fill 8192, sigma~90)
#define EPB   (N_EDGES/256)  // 6250 edges per scatter block

// ---------------- Layer-1 GEMM: y = x@Wrel, acc = x@Wroot + b ----------------

__global__ __launch_bounds__(256) void gemm50(const float* __restrict__ x,
        const float* __restrict__ Wrel, const float* __restrict__ Wroot,
        const float* __restrict__ b,
        float* __restrict__ y, float* __restrict__ acc) {
    __shared__ float sWrel[N_FEAT * HID];
    __shared__ float sWroot[N_FEAT * HID];
    for (int i = threadIdx.x; i < N_FEAT * HID; i += 256) {
        sWrel[i]  = Wrel[i];
        sWroot[i] = Wroot[i];
    }
    __syncthreads();
    int idx = blockIdx.x * 256 + threadIdx.x;
    if (idx >= N_NODES * HID) return;
    int n = idx / HID, j = idx % HID;
    const float* xr = x + n * N_FEAT;
    float a0 = 0.0f, a1 = b[j];
    #pragma unroll
    for (int k = 0; k < N_FEAT; ++k) {
        float xv = xr[k];
        a0 = fmaf(xv, sWrel[k * HID + j], a0);
        a1 = fmaf(xv, sWroot[k * HID + j], a1);
    }
    y[idx]   = a0;
    acc[idx] = a1;
}

// ---------------- CSR build: two-level LDS bucket sort, no per-edge global atomics ----

__global__ void init_cur(int* __restrict__ gcur) {
    int t = threadIdx.x;
    if (t < NBUCK) gcur[t] = t * BCAP;
}

// Stage 1: group edges by coarse bucket (dst>>8) into padded regions.
__global__ __launch_bounds__(1024) void bucket_scatter(const int* __restrict__ dst,
        const int* __restrict__ src, int* __restrict__ gcur,
        unsigned int* __restrict__ padded) {
    __shared__ unsigned int ep[EPB];
    __shared__ int cnt[NBUCK];
    __shared__ int cur[NBUCK];
    int t = threadIdx.x;
    for (int i = t; i < NBUCK; i += 1024) cnt[i] = 0;
    __syncthreads();
    int e0 = blockIdx.x * EPB;
    for (int i = t; i < EPB; i += 1024) {
        int d = dst[e0 + i];
        int s = src[e0 + i];
        ep[i] = ((unsigned int)d << 16) | (unsigned int)s;
        atomicAdd(&cnt[d >> 8], 1);
    }
    __syncthreads();
    if (t < NBUCK) cur[t] = atomicAdd(&gcur[t], cnt[t]);  // claim region (196 atomics)
    __syncthreads();
    for (int i = t; i < EPB; i += 1024) {
        unsigned int e = ep[i];
        int b = e >> 24;                    // dst>>8
        int p = atomicAdd(&cur[b], 1);      // LDS atomic -> global slot
        if (p < (b + 1) * BCAP) padded[p] = e;  // overflow guard (never fires)
    }
}

// Stage 2: within each bucket, group by node in place; emit per-node [start,end).
__global__ __launch_bounds__(256) void bucket_build(const int* __restrict__ gcur,
        unsigned int* __restrict__ padded,
        int* __restrict__ start, int* __restrict__ endp) {
    __shared__ unsigned int ep[BCAP];
    __shared__ int cnt[256];
    __shared__ int scn[256];
    __shared__ int cur[256];
    int g = blockIdx.x, t = threadIdx.x;
    int base = g * BCAP;
    int m = min(gcur[g] - base, BCAP);
    cnt[t] = 0;
    __syncthreads();
    for (int i = t; i < m; i += 256) {
        unsigned int e = padded[base + i];
        ep[i] = e;
        atomicAdd(&cnt[(e >> 16) & 255u], 1);
    }
    __syncthreads();
    int v = cnt[t];
    scn[t] = v;
    __syncthreads();
    for (int d = 1; d < 256; d <<= 1) {
        int u = (t >= d) ? scn[t - d] : 0;
        __syncthreads();
        scn[t] += u;
        __syncthreads();
    }
    int excl = scn[t] - v;
    cur[t] = excl;
    int node = g * 256 + t;
    if (node < N_NODES) {
        start[node] = base + excl;
        endp[node]  = base + excl + v;
    }
    __syncthreads();
    for (int i = t; i < m; i += 256) {
        unsigned int e = ep[i];
        int p = atomicAdd(&cur[(e >> 16) & 255u], 1);
        padded[base + p] = e & 0xFFFFu;     // store src only
    }
}

// ---------------- Fused gather + next-layer GEMM ----------------

__global__ __launch_bounds__(320) void gather_gemm(const int* __restrict__ offs,
        const int* __restrict__ cend, const int* __restrict__ csr,
        const float* __restrict__ y_in, const float* __restrict__ accp,
        const float* __restrict__ Wrel, const float* __restrict__ Wroot,
        const float* __restrict__ b,
        float* __restrict__ y_out, float* __restrict__ acc_out) {
    __shared__ float sWrel[HID * HID];
    __shared__ float sWroot[HID * HID];
    __shared__ float sb[HID];
    __shared__ float rh[64][HID];
    for (int i = threadIdx.x; i < HID * HID; i += 320) {
        sWrel[i]  = Wrel[i];
        sWroot[i] = Wroot[i];
    }
    if (threadIdx.x < HID) sb[threadIdx.x] = b[threadIdx.x];
    int local = threadIdx.x / 5;
    int q     = threadIdx.x % 5;
    int node  = blockIdx.x * 64 + local;
    bool valid = node < N_NODES;
    if (valid) {
        int a = offs[node], e = cend[node];
        float4 s0 = make_float4(0.f, 0.f, 0.f, 0.f);
        float4 s1 = make_float4(0.f, 0.f, 0.f, 0.f);
        int k = a;
        for (; k + 1 < e; k += 2) {
            int sn0 = csr[k], sn1 = csr[k + 1];
            float4 v0 = *(const float4*)(y_in + sn0 * HID + q * 4);
            float4 v1 = *(const float4*)(y_in + sn1 * HID + q * 4);
            s0.x += v0.x; s0.y += v0.y; s0.z += v0.z; s0.w += v0.w;
            s1.x += v1.x; s1.y += v1.y; s1.z += v1.z; s1.w += v1.w;
        }
        if (k < e) {
            int sn = csr[k];
            float4 v = *(const float4*)(y_in + sn * HID + q * 4);
            s0.x += v.x; s0.y += v.y; s0.z += v.z; s0.w += v.w;
        }
        float4 av = *((const float4*)(accp + node * HID) + q);
        rh[local][q * 4 + 0] = fmaxf(av.x + s0.x + s1.x, 0.f);
        rh[local][q * 4 + 1] = fmaxf(av.y + s0.y + s1.y, 0.f);
        rh[local][q * 4 + 2] = fmaxf(av.z + s0.z + s1.z, 0.f);
        rh[local][q * 4 + 3] = fmaxf(av.w + s0.w + s1.w, 0.f);
    }
    __syncthreads();
    if (!valid) return;
    int j0 = q * 4;
    float y0 = 0.f, y1 = 0.f, y2 = 0.f, y3 = 0.f;
    float a0 = sb[j0], a1 = sb[j0 + 1], a2 = sb[j0 + 2], a3 = sb[j0 + 3];
    #pragma unroll
    for (int k = 0; k < HID; ++k) {
        float hv = rh[local][k];
        const float* wr = sWrel  + k * HID + j0;
        const float* wo = sWroot + k * HID + j0;
        y0 = fmaf(hv, wr[0], y0); y1 = fmaf(hv, wr[1], y1);
        y2 = fmaf(hv, wr[2], y2); y3 = fmaf(hv, wr[3], y3);
        a0 = fmaf(hv, wo[0], a0); a1 = fmaf(hv, wo[1], a1);
        a2 = fmaf(hv, wo[2], a2); a3 = fmaf(hv, wo[3], a3);
    }
    *((float4*)(y_out   + node * HID) + q) = make_float4(y0, y1, y2, y3);
    *((float4*)(acc_out + node * HID) + q) = make_float4(a0, a1, a2, a3);
}

// Plain gather for final layer: acc[n] += sum y[src]
__global__ __launch_bounds__(320) void gather(const int* __restrict__ offs,
        const int* __restrict__ cend, const int* __restrict__ csr,
        const float* __restrict__ y, float* __restrict__ acc) {
    int node = blockIdx.x * 64 + threadIdx.x / 5;
    int q = threadIdx.x % 5;
    if (node >= N_NODES) return;
    int a = offs[node], e = cend[node];
    float4 s0 = make_float4(0.f, 0.f, 0.f, 0.f);
    float4 s1 = make_float4(0.f, 0.f, 0.f, 0.f);
    int k = a;
    for (; k + 1 < e; k += 2) {
        int sn0 = csr[k], sn1 = csr[k + 1];
        float4 v0 = *(const float4*)(y + sn0 * HID + q * 4);
        float4 v1 = *(const float4*)(y + sn1 * HID + q * 4);
        s0.x += v0.x; s0.y += v0.y; s0.z += v0.z; s0.w += v0.w;
        s1.x += v1.x; s1.y += v1.y; s1.z += v1.z; s1.w += v1.w;
    }
    if (k < e) {
        int sn = csr[k];
        float4 v = *(const float4*)(y + sn * HID + q * 4);
        s0.x += v.x; s0.y += v.y; s0.z += v.z; s0.w += v.w;
    }
    float4* ap = (float4*)(acc + node * HID) + q;
    float4 o = *ap;
    o.x += s0.x + s1.x; o.y += s0.y + s1.y;
    o.z += s0.z + s1.z; o.w += s0.w + s1.w;
    *ap = o;
}

// ---------------- Pool (block per graph, batch sorted) + final linear ----------------

__global__ __launch_bounds__(320) void pool_final(const float* __restrict__ acc,
        const int* __restrict__ batch, const float* __restrict__ Wlin,
        const float* __restrict__ blin, float* __restrict__ out) {
    int g = blockIdx.x;
    __shared__ int se[2];
    if (threadIdx.x < 2) {
        int target = g + threadIdx.x;
        int lo = 0, hi = N_NODES;
        while (lo < hi) {
            int mid = (lo + hi) >> 1;
            if (batch[mid] < target) lo = mid + 1; else hi = mid;
        }
        se[threadIdx.x] = lo;
    }
    __syncthreads();
    int s = se[0], e = se[1];
    int j = threadIdx.x % HID;
    int r = threadIdx.x / HID;
    float mx = 0.0f, sm = 0.0f;
    for (int n = s + r; n < e; n += 16) {
        float v = fmaxf(acc[n * HID + j], 0.0f);
        mx = fmaxf(mx, v);
        sm += v;
    }
    __shared__ float smx[16][HID];
    __shared__ float ssm[16][HID];
    smx[r][j] = mx;
    ssm[r][j] = sm;
    __syncthreads();
    if (threadIdx.x < HID) {
        float m = 0.0f, su = 0.0f;
        #pragma unroll
        for (int r2 = 0; r2 < 16; ++r2) {
            m = fmaxf(m, smx[r2][threadIdx.x]);
            su += ssm[r2][threadIdx.x];
        }
        smx[0][threadIdx.x] = m;
        ssm[0][threadIdx.x] = su / fmaxf((float)(e - s), 1.0f);
    }
    __syncthreads();
    if (threadIdx.x < OUT_DIM) {
        int o = threadIdx.x;
        float a = blin[o];
        #pragma unroll
        for (int jj = 0; jj < HID; ++jj) {
            a = fmaf(smx[0][jj], Wlin[jj * OUT_DIM + o], a);
            a = fmaf(ssm[0][jj], Wlin[(HID + jj) * OUT_DIM + o], a);
        }
        out[g * OUT_DIM + o] = a;
    }
}

extern "C" void kernel_launch(void* const* d_in, const int* in_sizes, int n_in,
                              void* d_out, int out_size, void* d_ws, size_t ws_size,
                              hipStream_t stream) {
    const float* x      = (const float*)d_in[0];
    const int*   ei     = (const int*)  d_in[1];
    const int*   batch  = (const int*)  d_in[2];
    const float* Wrel1  = (const float*)d_in[3];
    const float* Wroot1 = (const float*)d_in[4];
    const float* b1     = (const float*)d_in[5];
    const float* Wrel2  = (const float*)d_in[6];
    const float* Wroot2 = (const float*)d_in[7];
    const float* b2     = (const float*)d_in[8];
    const float* Wrel3  = (const float*)d_in[9];
    const float* Wroot3 = (const float*)d_in[10];
    const float* b3     = (const float*)d_in[11];
    const float* Wlin   = (const float*)d_in[12];
    const float* blin   = (const float*)d_in[13];
    float* out = (float*)d_out;

    char* ws = (char*)d_ws;
    const size_t NB = (size_t)N_NODES * HID * sizeof(float);       // 4,000,000 B
    const size_t PB = (size_t)NBUCK * BCAP * sizeof(int);          // 8,028,160 B
    float*        yA     = (float*)(ws);
    float*        yB     = (float*)(ws + NB);
    float*        accA   = (float*)(ws + 2 * NB);
    float*        accB   = (float*)(ws + 3 * NB);
    unsigned int* padded = (unsigned int*)(ws + 4 * NB);
    int*          start  = (int*)(ws + 4 * NB + PB);
    int*          endp   = start + N_NODES;
    int*          gcur   = endp + N_NODES;

    const int* src = ei;
    const int* dst = ei + N_EDGES;

    const int gN = (N_NODES * HID + 255) / 256;   // 3907
    const int gG = (N_NODES + 63) / 64;           // 782

    // ---- CSR build: two-level LDS bucket sort ----
    init_cur<<<1, 256, 0, stream>>>(gcur);
    bucket_scatter<<<256, 1024, 0, stream>>>(dst, src, gcur, padded);
    bucket_build<<<NBUCK, 256, 0, stream>>>(gcur, padded, start, endp);

    // ---- Layer 1 GEMM ----
    gemm50<<<gN, 256, 0, stream>>>(x, Wrel1, Wroot1, b1, yA, accA);
    // ---- Layer 1 gather fused with Layer 2 GEMM ----
    gather_gemm<<<gG, 320, 0, stream>>>(start, endp, (const int*)padded, yA, accA,
                                        Wrel2, Wroot2, b2, yB, accB);
    // ---- Layer 2 gather fused with Layer 3 GEMM ----
    gather_gemm<<<gG, 320, 0, stream>>>(start, endp, (const int*)padded, yB, accB,
                                        Wrel3, Wroot3, b3, yA, accA);
    // ---- Layer 3 gather ----
    gather<<<gG, 320, 0, stream>>>(start, endp, (const int*)padded, yA, accA);

    // ---- Pool + final linear ----
    pool_final<<<N_GRAPHS, 320, 0, stream>>>(accA, batch, Wlin, blin, out);
}

// Round 5
// 124.156 us; speedup vs baseline: 42.5407x; 1.3438x over previous
//
#include <hip/hip_runtime.h>

#define N_NODES  50000
#define N_EDGES  1600000
#define N_FEAT   50
#define HID      20
#define OUT_DIM  10
#define N_GRAPHS 64

#define NBUCK 196            // coarse buckets: dst >> 8 (256 nodes each)
#define BCAP  10240          // padded slots/bucket (avg fill 8163, 23 sigma margin)
#define EPB   (N_EDGES/256)  // 6250 edges per scatter block

// ---------------- init: gcur + pool accumulators ----------------

__global__ __launch_bounds__(1024) void init_all(int* __restrict__ gcur,
        float* __restrict__ gmax, float* __restrict__ gsum, float* __restrict__ gcnt) {
    int t = threadIdx.x;
    if (t < NBUCK) gcur[t] = t * BCAP;
    for (int i = t; i < N_GRAPHS * HID; i += 1024) { gmax[i] = 0.f; gsum[i] = 0.f; }
    if (t < N_GRAPHS) gcnt[t] = 0.f;
}

// ---------------- Layer-1 GEMM: y = x@Wrel, acc = x@Wroot + b ----------------

__global__ __launch_bounds__(256) void gemm50(const float* __restrict__ x,
        const float* __restrict__ Wrel, const float* __restrict__ Wroot,
        const float* __restrict__ b,
        float* __restrict__ y, float* __restrict__ acc) {
    __shared__ float sWrel[N_FEAT * HID];
    __shared__ float sWroot[N_FEAT * HID];
    for (int i = threadIdx.x; i < N_FEAT * HID; i += 256) {
        sWrel[i]  = Wrel[i];
        sWroot[i] = Wroot[i];
    }
    __syncthreads();
    int idx = blockIdx.x * 256 + threadIdx.x;
    if (idx >= N_NODES * HID) return;
    int n = idx / HID, j = idx % HID;
    const float* xr = x + n * N_FEAT;
    float a0 = 0.0f, a1 = b[j];
    #pragma unroll
    for (int k = 0; k < N_FEAT; ++k) {
        float xv = xr[k];
        a0 = fmaf(xv, sWrel[k * HID + j], a0);
        a1 = fmaf(xv, sWroot[k * HID + j], a1);
    }
    y[idx]   = a0;
    acc[idx] = a1;
}

// ---------------- CSR build stage 1: coarse bucket scatter (coalesced writes) ----

__global__ __launch_bounds__(1024) void bucket_scatter(const int* __restrict__ dst,
        const int* __restrict__ src, int* __restrict__ gcur,
        unsigned int* __restrict__ padded) {
    __shared__ unsigned int ep[EPB];    // staged edges
    __shared__ unsigned int ep2[EPB];   // bucket-sorted edges
    __shared__ int cnt[256];            // per-bucket count (padded to 256)
    __shared__ int scn[256];
    __shared__ int lofs[256];           // local exclusive offsets
    __shared__ int gbase[256];          // claimed global bases
    __shared__ int lcur[256];
    int t = threadIdx.x;
    if (t < 256) cnt[t] = 0;
    __syncthreads();
    int e0 = blockIdx.x * EPB;
    for (int i = t; i < EPB; i += 1024) {
        int d = dst[e0 + i];
        int s = src[e0 + i];
        ep[i] = ((unsigned int)d << 16) | (unsigned int)s;
        atomicAdd(&cnt[d >> 8], 1);
    }
    __syncthreads();
    if (t < 256) scn[t] = cnt[t];
    __syncthreads();
    for (int d = 1; d < 256; d <<= 1) {
        int u = 0;
        if (t < 256 && t >= d) u = scn[t - d];
        __syncthreads();
        if (t < 256) scn[t] += u;
        __syncthreads();
    }
    if (t < NBUCK) {
        int excl = scn[t] - cnt[t];
        lofs[t] = excl;
        lcur[t] = excl;
        gbase[t] = atomicAdd(&gcur[t], cnt[t]);   // 196 global atomics/block
    }
    __syncthreads();
    // reorder into bucket-grouped order
    for (int i = t; i < EPB; i += 1024) {
        unsigned int e = ep[i];
        int p = atomicAdd(&lcur[e >> 24], 1);
        ep2[p] = e;
    }
    __syncthreads();
    // coalesced write: consecutive i -> consecutive slots within each bucket run
    for (int i = t; i < EPB; i += 1024) {
        unsigned int e = ep2[i];
        int b = e >> 24;
        int gp = gbase[b] + (i - lofs[b]);
        if (gp < (b + 1) * BCAP) padded[gp] = e;  // overflow guard (never fires)
    }
}

// ---------------- CSR build stage 2: per-bucket counting sort -> ushort csr ----

__global__ __launch_bounds__(1024) void bucket_build(const int* __restrict__ gcur,
        const unsigned int* __restrict__ padded, unsigned short* __restrict__ csr16,
        int* __restrict__ start, int* __restrict__ endp) {
    __shared__ unsigned short eo[BCAP];   // 20 KB sorted output staging
    __shared__ int cnt4[4][256];          // privatized hist (4 wavegroups)
    __shared__ int cur4[4][256];
    __shared__ int scn[256];
    int g = blockIdx.x, t = threadIdx.x;
    int wg = t >> 8;
    int base = g * BCAP;
    int m = min(gcur[g] - base, BCAP);
    if (t < 256) { cnt4[0][t] = 0; cnt4[1][t] = 0; cnt4[2][t] = 0; cnt4[3][t] = 0; }
    __syncthreads();
    // pass 1: histogram (global re-read is L2-hot, frees LDS for privatization)
    for (int i = t; i < m; i += 1024)
        atomicAdd(&cnt4[wg][(padded[base + i] >> 16) & 255u], 1);
    __syncthreads();
    int c0 = 0, c1 = 0, c2 = 0, c3 = 0, tot = 0;
    if (t < 256) {
        c0 = cnt4[0][t]; c1 = cnt4[1][t]; c2 = cnt4[2][t]; c3 = cnt4[3][t];
        tot = c0 + c1 + c2 + c3;
        scn[t] = tot;
    }
    __syncthreads();
    for (int d = 1; d < 256; d <<= 1) {
        int u = 0;
        if (t < 256 && t >= d) u = scn[t - d];
        __syncthreads();
        if (t < 256) scn[t] += u;
        __syncthreads();
    }
    if (t < 256) {
        int excl = scn[t] - tot;
        cur4[0][t] = excl;
        cur4[1][t] = excl + c0;
        cur4[2][t] = excl + c0 + c1;
        cur4[3][t] = excl + c0 + c1 + c2;
        int node = g * 256 + t;
        if (node < N_NODES) {
            start[node] = base + excl;
            endp[node]  = base + excl + tot;
        }
    }
    __syncthreads();
    // pass 2: place src values grouped by node
    for (int i = t; i < m; i += 1024) {
        unsigned int e = padded[base + i];
        int p = atomicAdd(&cur4[wg][(e >> 16) & 255u], 1);
        eo[p] = (unsigned short)(e & 0xFFFFu);
    }
    __syncthreads();
    // pass 3: coalesced write of sorted bucket
    for (int i = t; i < m; i += 1024) csr16[base + i] = eo[i];
}

// ---------------- Fused gather + next-layer GEMM ----------------

__global__ __launch_bounds__(320) void gather_gemm(const int* __restrict__ offs,
        const int* __restrict__ cend, const unsigned short* __restrict__ csr,
        const float* __restrict__ y_in, const float* __restrict__ accp,
        const float* __restrict__ Wrel, const float* __restrict__ Wroot,
        const float* __restrict__ b,
        float* __restrict__ y_out, float* __restrict__ acc_out) {
    __shared__ float sWrel[HID * HID];
    __shared__ float sWroot[HID * HID];
    __shared__ float sb[HID];
    __shared__ float rh[64][HID];
    for (int i = threadIdx.x; i < HID * HID; i += 320) {
        sWrel[i]  = Wrel[i];
        sWroot[i] = Wroot[i];
    }
    if (threadIdx.x < HID) sb[threadIdx.x] = b[threadIdx.x];
    int local = threadIdx.x / 5;
    int q     = threadIdx.x % 5;
    int node  = blockIdx.x * 64 + local;
    bool valid = node < N_NODES;
    if (valid) {
        int a = offs[node], e = cend[node];
        float4 s0 = make_float4(0.f, 0.f, 0.f, 0.f);
        float4 s1 = make_float4(0.f, 0.f, 0.f, 0.f);
        int k = a;
        for (; k + 3 < e; k += 4) {
            int sn0 = csr[k], sn1 = csr[k + 1], sn2 = csr[k + 2], sn3 = csr[k + 3];
            float4 v0 = *(const float4*)(y_in + sn0 * HID + q * 4);
            float4 v1 = *(const float4*)(y_in + sn1 * HID + q * 4);
            float4 v2 = *(const float4*)(y_in + sn2 * HID + q * 4);
            float4 v3 = *(const float4*)(y_in + sn3 * HID + q * 4);
            s0.x += v0.x + v2.x; s0.y += v0.y + v2.y;
            s0.z += v0.z + v2.z; s0.w += v0.w + v2.w;
            s1.x += v1.x + v3.x; s1.y += v1.y + v3.y;
            s1.z += v1.z + v3.z; s1.w += v1.w + v3.w;
        }
        for (; k < e; ++k) {
            int sn = csr[k];
            float4 v = *(const float4*)(y_in + sn * HID + q * 4);
            s0.x += v.x; s0.y += v.y; s0.z += v.z; s0.w += v.w;
        }
        float4 av = *((const float4*)(accp + node * HID) + q);
        rh[local][q * 4 + 0] = fmaxf(av.x + s0.x + s1.x, 0.f);
        rh[local][q * 4 + 1] = fmaxf(av.y + s0.y + s1.y, 0.f);
        rh[local][q * 4 + 2] = fmaxf(av.z + s0.z + s1.z, 0.f);
        rh[local][q * 4 + 3] = fmaxf(av.w + s0.w + s1.w, 0.f);
    }
    __syncthreads();
    if (!valid) return;
    int j0 = q * 4;
    float y0 = 0.f, y1 = 0.f, y2 = 0.f, y3 = 0.f;
    float a0 = sb[j0], a1 = sb[j0 + 1], a2 = sb[j0 + 2], a3 = sb[j0 + 3];
    #pragma unroll
    for (int k = 0; k < HID; ++k) {
        float hv = rh[local][k];
        const float* wr = sWrel  + k * HID + j0;
        const float* wo = sWroot + k * HID + j0;
        y0 = fmaf(hv, wr[0], y0); y1 = fmaf(hv, wr[1], y1);
        y2 = fmaf(hv, wr[2], y2); y3 = fmaf(hv, wr[3], y3);
        a0 = fmaf(hv, wo[0], a0); a1 = fmaf(hv, wo[1], a1);
        a2 = fmaf(hv, wo[2], a2); a3 = fmaf(hv, wo[3], a3);
    }
    *((float4*)(y_out   + node * HID) + q) = make_float4(y0, y1, y2, y3);
    *((float4*)(acc_out + node * HID) + q) = make_float4(a0, a1, a2, a3);
}

// ---------------- Final gather fused with max/mean pooling partials ----------------

__global__ __launch_bounds__(320) void gather_pool(const int* __restrict__ offs,
        const int* __restrict__ cend, const unsigned short* __restrict__ csr,
        const float* __restrict__ y, const float* __restrict__ accp,
        const int* __restrict__ batch,
        float* __restrict__ gmax, float* __restrict__ gsum, float* __restrict__ gcnt) {
    __shared__ float bufA[64 * HID];   // fast: h staging ; boundary: pmax
    __shared__ float bufB[64 * HID];   // fast: [0..319] pm16, [320..639] ps16 ; boundary: psum
    __shared__ int   lcnt[64];
    int t = threadIdx.x;
    int local = t / 5;
    int q     = t % 5;
    int n0    = blockIdx.x * 64;
    int node  = n0 + local;
    int nvalid = min(64, N_NODES - n0);
    int nlast  = n0 + nvalid - 1;
    int g0   = batch[n0];
    int span = batch[nlast] - g0 + 1;
    bool valid = node < N_NODES;

    float v0 = 0.f, v1 = 0.f, v2 = 0.f, v3 = 0.f;
    if (valid) {
        int a = offs[node], e = cend[node];
        float4 s0 = make_float4(0.f, 0.f, 0.f, 0.f);
        float4 s1 = make_float4(0.f, 0.f, 0.f, 0.f);
        int k = a;
        for (; k + 3 < e; k += 4) {
            int sn0 = csr[k], sn1 = csr[k + 1], sn2 = csr[k + 2], sn3 = csr[k + 3];
            float4 w0 = *(const float4*)(y + sn0 * HID + q * 4);
            float4 w1 = *(const float4*)(y + sn1 * HID + q * 4);
            float4 w2 = *(const float4*)(y + sn2 * HID + q * 4);
            float4 w3 = *(const float4*)(y + sn3 * HID + q * 4);
            s0.x += w0.x + w2.x; s0.y += w0.y + w2.y;
            s0.z += w0.z + w2.z; s0.w += w0.w + w2.w;
            s1.x += w1.x + w3.x; s1.y += w1.y + w3.y;
            s1.z += w1.z + w3.z; s1.w += w1.w + w3.w;
        }
        for (; k < e; ++k) {
            int sn = csr[k];
            float4 w = *(const float4*)(y + sn * HID + q * 4);
            s0.x += w.x; s0.y += w.y; s0.z += w.z; s0.w += w.w;
        }
        float4 av = *((const float4*)(accp + node * HID) + q);
        v0 = fmaxf(av.x + s0.x + s1.x, 0.f);
        v1 = fmaxf(av.y + s0.y + s1.y, 0.f);
        v2 = fmaxf(av.z + s0.z + s1.z, 0.f);
        v3 = fmaxf(av.w + s0.w + s1.w, 0.f);
    }

    if (span == 1) {
        // fast path: whole block is one graph -> tree reduce
        int j0 = q * 4;
        bufA[local * HID + j0 + 0] = v0;
        bufA[local * HID + j0 + 1] = v1;
        bufA[local * HID + j0 + 2] = v2;
        bufA[local * HID + j0 + 3] = v3;   // invalid nodes wrote 0: harmless (relu>=0)
        __syncthreads();
        int j = t % HID, r = t / HID;      // r in 0..15
        float m = 0.f, s = 0.f;
        #pragma unroll
        for (int rr = 0; rr < 4; ++rr) {
            float hv = bufA[(r + rr * 16) * HID + j];
            m = fmaxf(m, hv);
            s += hv;
        }
        bufB[r * HID + j] = m;
        bufB[320 + r * HID + j] = s;
        __syncthreads();
        if (t < HID) {
            float mm = 0.f, ss = 0.f;
            #pragma unroll
            for (int rr = 0; rr < 16; ++rr) {
                mm = fmaxf(mm, bufB[rr * HID + t]);
                ss += bufB[320 + rr * HID + t];
            }
            atomicMax((int*)&gmax[g0 * HID + t], __float_as_int(mm));
            atomicAdd(&gsum[g0 * HID + t], ss);
        }
        if (t == 0) atomicAdd(&gcnt[g0], (float)nvalid);
    } else {
        // boundary path: LDS-atomic per (graph-local, feat), then per-slot global atomics
        for (int i = t; i < 64 * HID; i += 320) { bufA[i] = 0.f; bufB[i] = 0.f; }
        if (t < 64) lcnt[t] = 0;
        __syncthreads();
        if (valid) {
            int li = batch[node] - g0;
            int j0 = q * 4;
            atomicMax((int*)&bufA[li * HID + j0 + 0], __float_as_int(v0));
            atomicMax((int*)&bufA[li * HID + j0 + 1], __float_as_int(v1));
            atomicMax((int*)&bufA[li * HID + j0 + 2], __float_as_int(v2));
            atomicMax((int*)&bufA[li * HID + j0 + 3], __float_as_int(v3));
            atomicAdd(&bufB[li * HID + j0 + 0], v0);
            atomicAdd(&bufB[li * HID + j0 + 1], v1);
            atomicAdd(&bufB[li * HID + j0 + 2], v2);
            atomicAdd(&bufB[li * HID + j0 + 3], v3);
            if (q == 0) atomicAdd(&lcnt[li], 1);
        }
        __syncthreads();
        for (int i = t; i < span * HID; i += 320) {
            int li = i / HID, j = i % HID;
            atomicMax((int*)&gmax[(g0 + li) * HID + j], __float_as_int(bufA[i]));
            atomicAdd(&gsum[(g0 + li) * HID + j], bufB[i]);
        }
        if (t < span) atomicAdd(&gcnt[g0 + t], (float)lcnt[t]);
    }
}

// ---------------- Final linear on [max || mean] ----------------

__global__ __launch_bounds__(640) void final_lin(const float* __restrict__ gmax,
        const float* __restrict__ gsum, const float* __restrict__ gcnt,
        const float* __restrict__ Wlin, const float* __restrict__ blin,
        float* __restrict__ out) {
    __shared__ float sW[2 * HID * OUT_DIM];
    for (int i = threadIdx.x; i < 2 * HID * OUT_DIM; i += 640) sW[i] = Wlin[i];
    __syncthreads();
    int idx = threadIdx.x;
    if (idx >= N_GRAPHS * OUT_DIM) return;
    int g = idx / OUT_DIM, o = idx % OUT_DIM;
    float c = fmaxf(gcnt[g], 1.0f);
    float a = blin[o];
    #pragma unroll
    for (int j = 0; j < HID; ++j) {
        a = fmaf(gmax[g * HID + j], sW[j * OUT_DIM + o], a);
        a = fmaf(gsum[g * HID + j] / c, sW[(HID + j) * OUT_DIM + o], a);
    }
    out[idx] = a;
}

extern "C" void kernel_launch(void* const* d_in, const int* in_sizes, int n_in,
                              void* d_out, int out_size, void* d_ws, size_t ws_size,
                              hipStream_t stream) {
    const float* x      = (const float*)d_in[0];
    const int*   ei     = (const int*)  d_in[1];
    const int*   batch  = (const int*)  d_in[2];
    const float* Wrel1  = (const float*)d_in[3];
    const float* Wroot1 = (const float*)d_in[4];
    const float* b1     = (const float*)d_in[5];
    const float* Wrel2  = (const float*)d_in[6];
    const float* Wroot2 = (const float*)d_in[7];
    const float* b2     = (const float*)d_in[8];
    const float* Wrel3  = (const float*)d_in[9];
    const float* Wroot3 = (const float*)d_in[10];
    const float* b3     = (const float*)d_in[11];
    const float* Wlin   = (const float*)d_in[12];
    const float* blin   = (const float*)d_in[13];
    float* out = (float*)d_out;

    char* ws = (char*)d_ws;
    const size_t NB   = (size_t)N_NODES * HID * sizeof(float);        // 4,000,000 B
    const size_t PB   = (size_t)NBUCK * BCAP * sizeof(int);           // 8,028,160 B
    const size_t CB   = (size_t)NBUCK * BCAP * sizeof(unsigned short);// 4,014,080 B
    float*          yA     = (float*)(ws);
    float*          yB     = (float*)(ws + NB);
    float*          accA   = (float*)(ws + 2 * NB);
    float*          accB   = (float*)(ws + 3 * NB);
    unsigned int*   padded = (unsigned int*)(ws + 4 * NB);
    unsigned short* csr16  = (unsigned short*)(ws + 4 * NB + PB);
    int*            start  = (int*)(ws + 4 * NB + PB + CB);
    int*            endp   = start + N_NODES;
    int*            gcur   = endp + N_NODES;
    float*          gmax   = (float*)(gcur + NBUCK + 4);
    float*          gsum   = gmax + N_GRAPHS * HID;
    float*          gcnt   = gsum + N_GRAPHS * HID;

    const int* src = ei;
    const int* dst = ei + N_EDGES;

    const int gN = (N_NODES * HID + 255) / 256;   // 3907
    const int gG = (N_NODES + 63) / 64;           // 782

    // ---- CSR build: two-level LDS bucket sort ----
    init_all<<<1, 1024, 0, stream>>>(gcur, gmax, gsum, gcnt);
    bucket_scatter<<<256, 1024, 0, stream>>>(dst, src, gcur, padded);
    bucket_build<<<NBUCK, 1024, 0, stream>>>(gcur, padded, csr16, start, endp);

    // ---- Layer 1 GEMM ----
    gemm50<<<gN, 256, 0, stream>>>(x, Wrel1, Wroot1, b1, yA, accA);
    // ---- L1 gather + L2 GEMM ----
    gather_gemm<<<gG, 320, 0, stream>>>(start, endp, csr16, yA, accA,
                                        Wrel2, Wroot2, b2, yB, accB);
    // ---- L2 gather + L3 GEMM ----
    gather_gemm<<<gG, 320, 0, stream>>>(start, endp, csr16, yB, accB,
                                        Wrel3, Wroot3, b3, yA, accA);
    // ---- L3 gather + pooling partials ----
    gather_pool<<<gG, 320, 0, stream>>>(start, endp, csr16, yA, accA, batch,
                                        gmax, gsum, gcnt);
    // ---- final linear ----
    final_lin<<<1, 640, 0, stream>>>(gmax, gsum, gcnt, Wlin, blin, out);
}